// Round 6
// baseline (602.078 us; speedup 1.0000x reference)
//
#include <hip/hip_runtime.h>
#include <stdint.h>

// ---- problem constants ----
#define B_   8
#define SQ_  512
#define SK_  512
#define H_   768
#define NH_  12
#define DH_  64
#define BH_  (B_*NH_)          // 96 (b,h) pairs
#define M_   (B_*SQ_)          // 4096 rows for both hidden and context
#define NTOT (3*H_)            // 2304 fused QKV output columns
#define GRID_ 768              // 3 blocks/CU x 256 CUs, exact co-residency

typedef __attribute__((ext_vector_type(8))) short short8;
typedef __attribute__((ext_vector_type(4))) float floatx4;
typedef __attribute__((ext_vector_type(4))) unsigned int uint4v;
typedef __attribute__((ext_vector_type(4))) unsigned short ushort4v;

#define MFMA16(a, b, c) __builtin_amdgcn_mfma_f32_16x16x32_bf16((a), (b), (c), 0, 0, 0)

__device__ __forceinline__ unsigned short f2b(float f) {   // fp32 -> bf16 bits (RNE)
  union { float f; unsigned u; } c; c.f = f;
  unsigned r = (c.u + 0x7fffu + ((c.u >> 16) & 1u)) >> 16;
  return (unsigned short)r;
}
__device__ __forceinline__ float b2f(unsigned short u) {   // bf16 bits -> fp32
  union { float f; unsigned u; } c; c.u = ((unsigned)u) << 16;
  return c.f;
}
__device__ __forceinline__ short8 ld8(const unsigned short* p) {  // 16B vector load
  union { uint4v u; short8 s; } c;
  c.u = *(const uint4v*)p;
  return c.s;
}

// ---- device-scope grid barrier (requires all GRID_ blocks co-resident) ----
__device__ __forceinline__ void gsync(unsigned* c) {
  __syncthreads();
  if (threadIdx.x == 0) {
    __threadfence();   // release: write back this XCD's dirty L2 lines
    __hip_atomic_fetch_add(c, 1u, __ATOMIC_RELEASE, __HIP_MEMORY_SCOPE_AGENT);
    while (__hip_atomic_load(c, __ATOMIC_ACQUIRE, __HIP_MEMORY_SCOPE_AGENT) < GRID_)
      __builtin_amdgcn_s_sleep(2);
  }
  __syncthreads();
  __threadfence();     // acquire: invalidate stale L1/L2 before phase reads
}

// ---- segment bounds for the pack phase ----
#define SEG_X   (M_*H_)               // 3145728 (hidden)
#define SEG_XC  (2*SEG_X)             // 6291456 (end of context)
#define SEG_W1  (H_*H_)               // 589824
#define SEG_WE  (SEG_XC + 3*SEG_W1)   // 8060928
#define SEG_BE  (SEG_WE + NTOT)       // 8063232
#define SEG_PE  (SEG_BE + SQ_*DH_)    // 8096000 (pos bf16)

#define SCALE2 0.18033688011112042f   // (1/8) * log2(e)
#define CPAD 136                      // attn chunk row stride (128 + 8)

struct __align__(16) SMemG { unsigned short As[128][72]; unsigned short Bs[128][72]; };  // 36864 B
struct __align__(16) SMemA {
  unsigned short Sc[2][64][CPAD];   // 34816 B
  float mb2[SK_];                   // 2048 B
  float red[64][4];                 // 1024 B
};
union SMemU { SMemG g; SMemA a; };  // 37888 B -> 3 blocks/CU on 160 KiB LDS

// ---------------------------------------------------------------------------
// mega kernel: phase0 pack -> gsync -> phase1 qkv gemm -> gsync -> phase2 attn
// ---------------------------------------------------------------------------
__global__ __launch_bounds__(256, 3) void mega_kernel(
    const float* __restrict__ hid, const float* __restrict__ ctx,
    const int* __restrict__ mask,
    const float* __restrict__ Wq, const float* __restrict__ bq,
    const float* __restrict__ Wk, const float* __restrict__ bk,
    const float* __restrict__ Wv, const float* __restrict__ bv,
    const float* __restrict__ pos,
    unsigned short* __restrict__ Xh, unsigned short* __restrict__ Xc,
    unsigned short* __restrict__ Wa, float* __restrict__ Ba,
    unsigned short* __restrict__ Pb,
    unsigned short* __restrict__ qw, unsigned short* __restrict__ kw,
    unsigned short* __restrict__ vt,
    unsigned* __restrict__ bar, float* __restrict__ out)
{
  __shared__ SMemU sm;
  const int bx = blockIdx.x;
  const int tid = threadIdx.x;

  // ================= phase 0: pack fp32 -> bf16 (grid-strided) =============
  for (int v = bx * 256 + tid; v < SEG_PE / 4; v += GRID_ * 256) {
    int i = v * 4;
    if (i < SEG_X) {
      floatx4 val = *(const floatx4*)(hid + i);
      ushort4v o = { f2b(val.x), f2b(val.y), f2b(val.z), f2b(val.w) };
      *(ushort4v*)(Xh + i) = o;
    } else if (i < SEG_XC) {
      int j = i - SEG_X;
      floatx4 val = *(const floatx4*)(ctx + j);
      ushort4v o = { f2b(val.x), f2b(val.y), f2b(val.z), f2b(val.w) };
      *(ushort4v*)(Xc + j) = o;
    } else if (i < SEG_WE) {
      int j = i - SEG_XC;
      const float* src; int o;
      if (j < SEG_W1)        { src = Wq; o = j; }
      else if (j < 2*SEG_W1) { src = Wk; o = j - SEG_W1; }
      else                   { src = Wv; o = j - 2*SEG_W1; }
      floatx4 val = *(const floatx4*)(src + o);
      ushort4v ov = { f2b(val.x), f2b(val.y), f2b(val.z), f2b(val.w) };
      *(ushort4v*)(Wa + j) = ov;
    } else if (i < SEG_BE) {
      int j = i - SEG_WE;
      #pragma unroll
      for (int t = 0; t < 4; ++t) {
        int jj = j + t;
        float val = (jj < H_) ? bq[jj] : (jj < 2*H_) ? bk[jj - H_] : bv[jj - 2*H_];
        Ba[jj] = val;
      }
    } else {
      int j = i - SEG_BE;
      floatx4 val = *(const floatx4*)(pos + j);
      ushort4v o = { f2b(val.x), f2b(val.y), f2b(val.z), f2b(val.w) };
      *(ushort4v*)(Pb + j) = o;
    }
  }

  gsync(bar + 0);

  // ================= phase 1: fused QKV projection GEMM ====================
  // M=4096 x N=2304 x K=768, 128x128 tiles, blocks 0..575 active.
  if (bx < 576) {
    int xcd = bx & 7, j = bx >> 3;            // XCD-swizzled tile mapping
    int bm = (xcd >> 1) * 8 + j / 9;          // 32 m-tiles
    int bn = (xcd & 1) * 9 + j % 9;           // 18 n-tiles
    const unsigned short* X = (bn < 6) ? Xh : Xc;
    bool isV = (bn >= 12);
    int m0 = bm * 128, n0 = bn * 128;

    int lane = tid & 63, wave = tid >> 6;
    int wm = (wave & 1) * 64, wn = (wave >> 1) * 64;
    int lc16 = lane & 15, quad = lane >> 4, kk = quad * 8;
    int srow = tid >> 3, sch = (tid & 7) * 8;

    unsigned short (*TA)[72] = isV ? sm.g.As : sm.g.Bs;
    unsigned short (*TB)[72] = isV ? sm.g.Bs : sm.g.As;
    int oa = isV ? wm : wn;
    int ob = isV ? wn : wm;

    floatx4 acc[4][4];
    #pragma unroll
    for (int i = 0; i < 4; ++i)
      #pragma unroll
      for (int jj = 0; jj < 4; ++jj) acc[i][jj] = (floatx4){0.f, 0.f, 0.f, 0.f};

    uint4v a[4], b[4];
    #pragma unroll
    for (int rp = 0; rp < 4; ++rp) {
      a[rp] = *(const uint4v*)&X[(m0 + srow + rp * 32) * H_ + sch];
      b[rp] = *(const uint4v*)&Wa[(n0 + srow + rp * 32) * H_ + sch];
    }

    for (int k0 = 0; k0 < H_; k0 += 64) {
      __syncthreads();
      #pragma unroll
      for (int rp = 0; rp < 4; ++rp) {
        *(uint4v*)&sm.g.As[srow + rp * 32][sch] = a[rp];
        *(uint4v*)&sm.g.Bs[srow + rp * 32][sch] = b[rp];
      }
      __syncthreads();

      if (k0 + 64 < H_) {
        #pragma unroll
        for (int rp = 0; rp < 4; ++rp) {
          a[rp] = *(const uint4v*)&X[(m0 + srow + rp * 32) * H_ + k0 + 64 + sch];
          b[rp] = *(const uint4v*)&Wa[(n0 + srow + rp * 32) * H_ + k0 + 64 + sch];
        }
      }

      #pragma unroll
      for (int s = 0; s < 2; ++s) {
        short8 af[4], bf[4];
        #pragma unroll
        for (int i = 0; i < 4; ++i) af[i] = ld8(&TA[oa + i * 16 + lc16][s * 32 + kk]);
        #pragma unroll
        for (int i = 0; i < 4; ++i) bf[i] = ld8(&TB[ob + i * 16 + lc16][s * 32 + kk]);
        #pragma unroll
        for (int mi = 0; mi < 4; ++mi)
          #pragma unroll
          for (int ni = 0; ni < 4; ++ni)
            acc[mi][ni] = MFMA16(af[mi], bf[ni], acc[mi][ni]);
      }
    }

    if (!isV) {
      #pragma unroll
      for (int mi = 0; mi < 4; ++mi) {
        #pragma unroll
        for (int ni = 0; ni < 4; ++ni) {
          int gn0 = n0 + wn + mi * 16 + quad * 4;     // 4 consecutive features
          int gs  = m0 + wm + ni * 16 + lc16;         // sequence index
          int bidx = gs >> 9, s0 = gs & 511;
          floatx4 bv4 = *(const floatx4*)&Ba[gn0];
          ushort4v o;
          if (gn0 < H_) {                              // Q
            int h = gn0 >> 6, d0 = gn0 & 63;
            #pragma unroll
            for (int r = 0; r < 4; ++r) o[r] = f2b(acc[mi][ni][r] + bv4[r]);
            *(ushort4v*)(qw + (((bidx * NH_ + h) << 9) + s0) * DH_ + d0) = o;
          } else {                                     // K (+ bf16 pos_k)
            int g = gn0 - H_;
            int h = g >> 6, d0 = g & 63;
            ushort4v pk = *(const ushort4v*)(Pb + s0 * DH_ + d0);
            #pragma unroll
            for (int r = 0; r < 4; ++r) o[r] = f2b(acc[mi][ni][r] + bv4[r] + b2f(pk[r]));
            *(ushort4v*)(kw + (((bidx * NH_ + h) << 9) + s0) * DH_ + d0) = o;
          }
        }
      }
    } else {
      #pragma unroll
      for (int mi = 0; mi < 4; ++mi) {
        #pragma unroll
        for (int ni = 0; ni < 4; ++ni) {
          int gm0 = m0 + wm + mi * 16 + quad * 4;
          int gn  = n0 + wn + ni * 16 + lc16;
          float bv = Ba[gn];
          int bidx = gm0 >> 9, s0 = gm0 & 511;
          int g = gn - 2 * H_;
          int h = g >> 6, d = g & 63;
          ushort4v pk;
          #pragma unroll
          for (int r = 0; r < 4; ++r) pk[r] = f2b(acc[mi][ni][r] + bv);
          *(ushort4v*)(vt + ((bidx * NH_ + h) * DH_ + d) * SK_ + s0) = pk;
        }
      }
    }
  }

  gsync(bar + 1);

  // ================= phase 2: attention (fused softmax) ====================
  {
    int bh = bx % 96, qt = bx / 96;          // XCD-friendly: bx%8 == bh%8
    int b = bh / NH_, h = bh - b * NH_;
    int lane = tid & 63, wave = tid >> 6;
    int lc16 = lane & 15, quad = lane >> 4, kk = quad * 8;

    for (int i = tid; i < SK_; i += 256)
      sm.a.mb2[i] = mask[(b << 9) + i] ? 0.0f : -100000.0f;

    // B-operand frags (held all QK phases): 4 row-tiles x (2 q + 2 pos_q)
    const unsigned short* qbase = qw + ((bh << 9) + qt * 64) * DH_;
    const unsigned short* pqb   = Pb + (qt * 64) * DH_;
    short8 aq[4][2], ap[4][2];
    #pragma unroll
    for (int rt = 0; rt < 4; ++rt) {
      const unsigned short* qr = qbase + (rt * 16 + lc16) * DH_;
      const unsigned short* pr = pqb + (rt * 16 + lc16) * DH_;
      aq[rt][0] = ld8(qr + kk);
      aq[rt][1] = ld8(qr + 32 + kk);
      ap[rt][0] = ld8(pr + kk);
      ap[rt][1] = ld8(pr + 32 + kk);
    }

    const unsigned short* kwb = kw + ((bh << 9)) * DH_;
    const unsigned short* vb0 = vt + (bh * DH_ + wave * 16 + lc16) * SK_;
    float rs[4] = {0.f, 0.f, 0.f, 0.f};
    floatx4 o[4];
    #pragma unroll
    for (int i = 0; i < 4; ++i) o[i] = (floatx4){0.f, 0.f, 0.f, 0.f};

    // prefetch K/pos step 0
    short8 cb0, cb1, cp0, cp1, nb0, nb1, np0, np1;
    {
      int kcol = wave * 32;
      const unsigned short* kb = kwb + kcol * DH_;
      const unsigned short* pb = Pb + kcol * DH_;
      cb0 = ld8(kb + lc16 * DH_ + kk);
      cb1 = ld8(kb + lc16 * DH_ + 32 + kk);
      cp0 = ld8(pb + lc16 * DH_ + kk);
      cp1 = ld8(pb + lc16 * DH_ + 32 + kk);
    }

    __syncthreads();   // mb2 ready

    for (int chunk = 0; chunk < 4; ++chunk) {
      unsigned short (*S)[CPAD] = sm.a.Sc[chunk & 1];

      short8 vf[4];
      #pragma unroll
      for (int ks = 0; ks < 4; ++ks) vf[ks] = ld8(vb0 + chunk * 128 + ks * 32 + kk);

      #pragma unroll
      for (int ct = 0; ct < 2; ++ct) {
        int s = chunk * 2 + ct;
        if (s < 7) {   // prefetch next step's K/pos frags
          int kcol = ((s + 1) >> 1) * 128 + wave * 32 + ((s + 1) & 1) * 16;
          const unsigned short* kb = kwb + kcol * DH_;
          const unsigned short* pb = Pb + kcol * DH_;
          nb0 = ld8(kb + lc16 * DH_ + kk);
          nb1 = ld8(kb + lc16 * DH_ + 32 + kk);
          np0 = ld8(pb + lc16 * DH_ + kk);
          np1 = ld8(pb + lc16 * DH_ + 32 + kk);
        }
        int kcol = chunk * 128 + wave * 32 + ct * 16;
        floatx4 mk = *(const floatx4*)&sm.a.mb2[kcol + quad * 4];
        floatx4 c[4];
        #pragma unroll
        for (int rt = 0; rt < 4; ++rt) {
          c[rt] = (floatx4){0.f, 0.f, 0.f, 0.f};
          c[rt] = MFMA16(cb0, aq[rt][0], c[rt]);   // A=K-tile, B=Q-rows
          c[rt] = MFMA16(cb1, aq[rt][1], c[rt]);
          c[rt] = MFMA16(cp0, ap[rt][0], c[rt]);
          c[rt] = MFMA16(cp1, ap[rt][1], c[rt]);
        }
        int lcol = wave * 32 + ct * 16 + quad * 4;
        #pragma unroll
        for (int rt = 0; rt < 4; ++rt) {
          ushort4v pv;
          float sum = 0.f;
          #pragma unroll
          for (int r = 0; r < 4; ++r) {
            float e = __builtin_exp2f(c[rt][r] * SCALE2 + mk[r]);
            sum += e;
            pv[r] = f2b(e);
          }
          rs[rt] += sum;
          *(ushort4v*)&S[rt * 16 + lc16][lcol] = pv;
        }
        cb0 = nb0; cb1 = nb1; cp0 = np0; cp1 = np1;
      }
      __syncthreads();   // probs chunk ready (prior chunk fully consumed)

      #pragma unroll
      for (int ks = 0; ks < 4; ++ks) {
        #pragma unroll
        for (int rt = 0; rt < 4; ++rt) {
          short8 pa = ld8(&S[rt * 16 + lc16][ks * 32 + kk]);
          o[rt] = MFMA16(pa, vf[ks], o[rt]);
        }
      }
      // no second barrier: next chunk writes the other Sc buffer
    }

    // ---- row-sum: reduce across quads, then across waves via LDS ----
    #pragma unroll
    for (int rt = 0; rt < 4; ++rt) {
      rs[rt] += __shfl_xor(rs[rt], 16, 64);
      rs[rt] += __shfl_xor(rs[rt], 32, 64);
    }
    if (quad == 0) {
      #pragma unroll
      for (int rt = 0; rt < 4; ++rt) sm.a.red[rt * 16 + lc16][wave] = rs[rt];
    }
    __syncthreads();

    #pragma unroll
    for (int rt = 0; rt < 4; ++rt) {
      #pragma unroll
      for (int r = 0; r < 4; ++r) {
        int sl = rt * 16 + quad * 4 + r;
        float inv = 1.0f / (sm.a.red[sl][0] + sm.a.red[sl][1] + sm.a.red[sl][2] + sm.a.red[sl][3]);
        int s = qt * 64 + sl;
        out[((b << 9) + s) * H_ + h * DH_ + wave * 16 + lc16] = o[rt][r] * inv;
      }
    }
  }
}

// ---------------------------------------------------------------------------
// host launcher
// ---------------------------------------------------------------------------
extern "C" void kernel_launch(void* const* d_in, const int* in_sizes, int n_in,
                              void* d_out, int out_size, void* d_ws, size_t ws_size,
                              hipStream_t stream) {
  (void)in_sizes; (void)n_in; (void)out_size; (void)ws_size;
  const float* hid  = (const float*)d_in[0];
  const float* ctx  = (const float*)d_in[1];
  const int*   mask = (const int*)d_in[2];
  const float* Wq   = (const float*)d_in[3];
  const float* bq   = (const float*)d_in[4];
  const float* Wk   = (const float*)d_in[5];
  const float* bk   = (const float*)d_in[6];
  const float* Wv   = (const float*)d_in[7];
  const float* bv   = (const float*)d_in[8];
  const float* pos  = (const float*)d_in[9];

  char* ws = (char*)d_ws;
  size_t off = 0;
  auto alloc = [&](size_t bytes) { char* p = ws + off; off = (off + bytes + 255) & ~(size_t)255; return p; };
  unsigned*       bar = (unsigned*)alloc(256);
  unsigned short* Xh = (unsigned short*)alloc((size_t)SEG_X * 2);
  unsigned short* Xc = (unsigned short*)alloc((size_t)SEG_X * 2);
  unsigned short* Wa = (unsigned short*)alloc((size_t)3 * SEG_W1 * 2);
  float*          Ba = (float*)alloc((size_t)NTOT * 4);
  unsigned short* qw = (unsigned short*)alloc((size_t)BH_ * SQ_ * DH_ * 2);
  unsigned short* kw = (unsigned short*)alloc((size_t)BH_ * SK_ * DH_ * 2);
  unsigned short* vt = (unsigned short*)alloc((size_t)BH_ * DH_ * SK_ * 2);
  unsigned short* Pb = (unsigned short*)alloc((size_t)SQ_ * DH_ * 2);

  hipMemsetAsync(bar, 0, 256, stream);   // zero the grid-barrier counters
  mega_kernel<<<GRID_, 256, 0, stream>>>(hid, ctx, mask, Wq, bq, Wk, bk, Wv, bv, pos,
                                         Xh, Xc, Wa, Ba, Pb, qw, kw, vt,
                                         bar, (float*)d_out);
}

// Round 7
// 160.846 us; speedup vs baseline: 3.7432x; 3.7432x over previous
//
#include <hip/hip_runtime.h>
#include <stdint.h>

// ---- problem constants ----
#define B_   8
#define SQ_  512
#define SK_  512
#define H_   768
#define NH_  12
#define DH_  64
#define BH_  (B_*NH_)          // 96 (b,h) pairs
#define M_   (B_*SQ_)          // 4096 rows for both hidden and context
#define NTOT (3*H_)            // 2304 fused QKV output columns

typedef __attribute__((ext_vector_type(8))) short short8;
typedef __attribute__((ext_vector_type(4))) float floatx4;
typedef __attribute__((ext_vector_type(4))) unsigned int uint4v;
typedef __attribute__((ext_vector_type(4))) unsigned short ushort4v;

#define MFMA16(a, b, c) __builtin_amdgcn_mfma_f32_16x16x32_bf16((a), (b), (c), 0, 0, 0)

typedef const __attribute__((address_space(1))) unsigned int glb_uint;
typedef __attribute__((address_space(3))) unsigned int lds_uint;
// async 16B global->LDS: per-lane global addr, LDS dest = uniform base + lane*16
#define GLL(gptr, lptr) \
  __builtin_amdgcn_global_load_lds((glb_uint*)(gptr), (lds_uint*)(lptr), 16, 0, 0)

__device__ __forceinline__ unsigned short f2b(float f) {   // fp32 -> bf16 bits (RNE)
  union { float f; unsigned u; } c; c.f = f;
  unsigned r = (c.u + 0x7fffu + ((c.u >> 16) & 1u)) >> 16;
  return (unsigned short)r;
}
__device__ __forceinline__ float b2f(unsigned short u) {   // bf16 bits -> fp32
  union { float f; unsigned u; } c; c.u = ((unsigned)u) << 16;
  return c.f;
}
__device__ __forceinline__ short8 ld8(const unsigned short* p) {  // 16B vector load
  union { uint4v u; short8 s; } c;
  c.u = *(const uint4v*)p;
  return c.s;
}

// ---------------------------------------------------------------------------
// Kernel 1: pack fp32 inputs -> bf16 workspace (hidden, context, W, pos, biases)
// ---------------------------------------------------------------------------
#define SEG_X   (M_*H_)          // 3145728 (hidden)
#define SEG_XC  (2*SEG_X)        // 6291456 (end of context)
#define SEG_W1  (H_*H_)          // 589824
#define SEG_WE  (SEG_XC + 3*SEG_W1)   // 8060928
#define SEG_BE  (SEG_WE + NTOT)  // 8063232
#define SEG_PE  (SEG_BE + SQ_*DH_)    // 8096000 (pos bf16)

__global__ __launch_bounds__(256) void pack_kernel(
    const float* __restrict__ hid, const float* __restrict__ ctx,
    const float* __restrict__ Wq, const float* __restrict__ Wk, const float* __restrict__ Wv,
    const float* __restrict__ bq, const float* __restrict__ bk, const float* __restrict__ bv,
    const float* __restrict__ pos,
    unsigned short* __restrict__ Xh, unsigned short* __restrict__ Xc,
    unsigned short* __restrict__ Wa, float* __restrict__ Ba,
    unsigned short* __restrict__ Pb)
{
  int i = (blockIdx.x * 256 + threadIdx.x) * 4;
  if (i < SEG_X) {
    floatx4 v = *(const floatx4*)(hid + i);
    ushort4v o = { f2b(v.x), f2b(v.y), f2b(v.z), f2b(v.w) };
    *(ushort4v*)(Xh + i) = o;
  } else if (i < SEG_XC) {
    int j = i - SEG_X;
    floatx4 v = *(const floatx4*)(ctx + j);
    ushort4v o = { f2b(v.x), f2b(v.y), f2b(v.z), f2b(v.w) };
    *(ushort4v*)(Xc + j) = o;
  } else if (i < SEG_WE) {
    int j = i - SEG_XC;
    const float* src; int o;
    if (j < SEG_W1)        { src = Wq; o = j; }
    else if (j < 2*SEG_W1) { src = Wk; o = j - SEG_W1; }
    else                   { src = Wv; o = j - 2*SEG_W1; }
    floatx4 v = *(const floatx4*)(src + o);
    ushort4v ov = { f2b(v.x), f2b(v.y), f2b(v.z), f2b(v.w) };
    *(ushort4v*)(Wa + j) = ov;
  } else if (i < SEG_BE) {
    int j = i - SEG_WE;
    #pragma unroll
    for (int t = 0; t < 4; ++t) {
      int jj = j + t;
      float v = (jj < H_) ? bq[jj] : (jj < 2*H_) ? bk[jj - H_] : bv[jj - 2*H_];
      Ba[jj] = v;
    }
  } else if (i < SEG_PE) {
    int j = i - SEG_BE;
    floatx4 v = *(const floatx4*)(pos + j);
    ushort4v o = { f2b(v.x), f2b(v.y), f2b(v.z), f2b(v.w) };
    *(ushort4v*)(Pb + j) = o;
  }
}

// ---------------------------------------------------------------------------
// Kernel 2: fused QKV projection GEMM (bf16 MFMA), M=4096 x N=2304 x K=768
//   Staging via global_load_lds width=16 into UNPADDED [128][64] LDS tiles
//   with XOR chunk swizzle: row r's 16B chunk c lives at chunk (c ^ (r&7)).
//   - global source: chunks permuted within each 128B row -> still coalesced
//   - staging dest: lane-linear (wave-uniform base + lane*16)  [HW rule]
//   - frag ds_read_b128: 8 distinct banksets per 8-lane phase -> conflict-free
// ---------------------------------------------------------------------------
__global__ __launch_bounds__(256) void qkv_gemm(
    const unsigned short* __restrict__ Xh, const unsigned short* __restrict__ Xc,
    const unsigned short* __restrict__ W,  const float* __restrict__ bias,
    const unsigned short* __restrict__ Pb,
    unsigned short* __restrict__ qw, unsigned short* __restrict__ kw,
    unsigned short* __restrict__ vt)
{
  __shared__ unsigned short As[128 * 64];   // 16 KB, swizzled
  __shared__ unsigned short Bs[128 * 64];   // 16 KB, swizzled

  int bx = blockIdx.x;
  int xcd = bx & 7, j = bx >> 3;            // XCD-swizzled tile mapping
  int bm = (xcd >> 1) * 8 + j / 9;          // 32 m-tiles
  int bn = (xcd & 1) * 9 + j % 9;           // 18 n-tiles
  const unsigned short* X = (bn < 6) ? Xh : Xc;
  bool isV = (bn >= 12);
  int m0 = bm * 128, n0 = bn * 128;

  int tid = threadIdx.x;
  int lane = tid & 63, wave = tid >> 6;
  int wm = (wave & 1) * 64, wn = (wave >> 1) * 64;
  int lc16 = lane & 15, quad = lane >> 4, kk = quad * 8;
  int sx7 = lc16 & 7;                       // frag-read swizzle key

  // staging geometry: round t covers chunks [t*256+wave*64, +64)
  int chl = wave * 64 + lane;               // chunk within round
  int sr = chl >> 3;                        // row contribution (rounds add 32)
  int scc = (chl & 7) ^ (sr & 7);           // swizzled global chunk
  int gcol = scc * 8;                       // global col offset (shorts)

  unsigned short (*TAp)[1] = nullptr; (void)TAp;
  const unsigned short* TA = isV ? As : Bs;
  const unsigned short* TB = isV ? Bs : As;
  int oa = isV ? wm : wn;
  int ob = isV ? wn : wm;

  floatx4 acc[4][4];
  #pragma unroll
  for (int i = 0; i < 4; ++i)
    #pragma unroll
    for (int jj = 0; jj < 4; ++jj) acc[i][jj] = (floatx4){0.f, 0.f, 0.f, 0.f};

  for (int k0 = 0; k0 < H_; k0 += 64) {
    __syncthreads();   // prior MFMA reads done
    #pragma unroll
    for (int t = 0; t < 4; ++t) {
      int r = t * 32 + sr;                      // tile row this lane stages
      unsigned short* la = As + (t * 256 + wave * 64) * 8;
      unsigned short* lb = Bs + (t * 256 + wave * 64) * 8;
      GLL(X + (m0 + r) * H_ + k0 + gcol, la);
      GLL(W + (n0 + r) * H_ + k0 + gcol, lb);
    }
    __syncthreads();   // vmcnt(0) drain: LDS tiles ready

    #pragma unroll
    for (int s = 0; s < 2; ++s) {
      int cs = s * 4 + quad;                    // unswizzled chunk of this frag
      short8 af[4], bf[4];
      #pragma unroll
      for (int i = 0; i < 4; ++i)
        af[i] = ld8(&TA[(oa + i * 16 + lc16) * 64 + ((cs ^ sx7) * 8)]);
      #pragma unroll
      for (int i = 0; i < 4; ++i)
        bf[i] = ld8(&TB[(ob + i * 16 + lc16) * 64 + ((cs ^ sx7) * 8)]);
      #pragma unroll
      for (int mi = 0; mi < 4; ++mi)
        #pragma unroll
        for (int ni = 0; ni < 4; ++ni)
          acc[mi][ni] = MFMA16(af[mi], bf[ni], acc[mi][ni]);
    }
  }

  if (!isV) {
    // D row (quad*4+r) = feature n, D col (lc16) = sequence m
    #pragma unroll
    for (int mi = 0; mi < 4; ++mi) {
      #pragma unroll
      for (int ni = 0; ni < 4; ++ni) {
        int gn0 = n0 + wn + mi * 16 + quad * 4;     // 4 consecutive features
        int gs  = m0 + wm + ni * 16 + lc16;         // sequence index
        int bidx = gs >> 9, s0 = gs & 511;
        floatx4 bv4 = *(const floatx4*)&bias[gn0];
        ushort4v o;
        if (gn0 < H_) {                              // Q
          int h = gn0 >> 6, d0 = gn0 & 63;
          #pragma unroll
          for (int r = 0; r < 4; ++r) o[r] = f2b(acc[mi][ni][r] + bv4[r]);
          *(ushort4v*)(qw + (((bidx * NH_ + h) << 9) + s0) * DH_ + d0) = o;
        } else {                                     // K (+ bf16 pos_k)
          int g = gn0 - H_;
          int h = g >> 6, d0 = g & 63;
          ushort4v pk = *(const ushort4v*)(Pb + s0 * DH_ + d0);
          #pragma unroll
          for (int r = 0; r < 4; ++r) o[r] = f2b(acc[mi][ni][r] + bv4[r] + b2f(pk[r]));
          *(ushort4v*)(kw + (((bidx * NH_ + h) << 9) + s0) * DH_ + d0) = o;
        }
      }
    }
  } else {
    // D row = sequence m (4 consecutive s), D col = feature n
    #pragma unroll
    for (int mi = 0; mi < 4; ++mi) {
      #pragma unroll
      for (int ni = 0; ni < 4; ++ni) {
        int gm0 = m0 + wm + mi * 16 + quad * 4;
        int gn  = n0 + wn + ni * 16 + lc16;
        float bv = bias[gn];
        int bidx = gm0 >> 9, s0 = gm0 & 511;
        int g = gn - 2 * H_;
        int h = g >> 6, d = g & 63;
        ushort4v pk;
        #pragma unroll
        for (int r = 0; r < 4; ++r) pk[r] = f2b(acc[mi][ni][r] + bv);
        *(ushort4v*)(vt + ((bidx * NH_ + h) * DH_ + d) * SK_ + s0) = pk;
      }
    }
  }
}

// ---------------------------------------------------------------------------
// Kernel 3: attention, softmax fused into QK epilogue (no max pass).
//   block index: bh = bx % 96, qt = bx / 96  -> all 8 q-tiles of one bh share
//   bx mod 8 (round-robin XCD) -> K/V stay L2-resident across q-tiles.
//   Double-buffered prob chunks (one barrier per chunk); K/pos frag loads
//   software-pipelined one step ahead; V frags issued before QK phase.
// ---------------------------------------------------------------------------
#define SCALE2 0.18033688011112042f   // (1/8) * log2(e)
#define CPAD 136                      // chunk row stride (128 + 8)

__global__ __launch_bounds__(256) void attn_kernel(
    const unsigned short* __restrict__ qw, const unsigned short* __restrict__ kw,
    const unsigned short* __restrict__ vt, const unsigned short* __restrict__ posb,
    const int* __restrict__ mask, float* __restrict__ out)
{
  __shared__ unsigned short Sc[2][64][CPAD];  // bf16 probs, double-buffered chunks
  __shared__ float mb2[SK_];                  // mask bias in exp2 domain
  __shared__ float red[64][4];                // per-wave row-sum partials

  int bx = blockIdx.x;
  int bh = bx % 96, qt = bx / 96;          // XCD-friendly: bx%8 == bh%8
  int b = bh / NH_, h = bh - b * NH_;
  int tid = threadIdx.x, lane = tid & 63, wave = tid >> 6;
  int lc16 = lane & 15, quad = lane >> 4, kk = quad * 8;

  for (int i = tid; i < SK_; i += 256)
    mb2[i] = mask[(b << 9) + i] ? 0.0f : -100000.0f;

  // B-operand frags (held all QK phases): 4 row-tiles x (2 q + 2 pos_q)
  const unsigned short* qbase = qw + ((bh << 9) + qt * 64) * DH_;
  const unsigned short* pqb   = posb + (qt * 64) * DH_;
  short8 aq[4][2], ap[4][2];
  #pragma unroll
  for (int rt = 0; rt < 4; ++rt) {
    const unsigned short* qr = qbase + (rt * 16 + lc16) * DH_;
    const unsigned short* pr = pqb + (rt * 16 + lc16) * DH_;
    aq[rt][0] = ld8(qr + kk);
    aq[rt][1] = ld8(qr + 32 + kk);
    ap[rt][0] = ld8(pr + kk);
    ap[rt][1] = ld8(pr + 32 + kk);
  }

  const unsigned short* kwb = kw + ((bh << 9)) * DH_;
  const unsigned short* vb0 = vt + (bh * DH_ + wave * 16 + lc16) * SK_;
  float rs[4] = {0.f, 0.f, 0.f, 0.f};      // per-lane row-sum partials
  floatx4 o[4];
  #pragma unroll
  for (int i = 0; i < 4; ++i) o[i] = (floatx4){0.f, 0.f, 0.f, 0.f};

  // prefetch K/pos step 0
  short8 cb0, cb1, cp0, cp1, nb0, nb1, np0, np1;
  {
    int kcol = wave * 32;
    const unsigned short* kb = kwb + kcol * DH_;
    const unsigned short* pb = posb + kcol * DH_;
    cb0 = ld8(kb + lc16 * DH_ + kk);
    cb1 = ld8(kb + lc16 * DH_ + 32 + kk);
    cp0 = ld8(pb + lc16 * DH_ + kk);
    cp1 = ld8(pb + lc16 * DH_ + 32 + kk);
  }

  __syncthreads();   // mb2 ready

  for (int chunk = 0; chunk < 4; ++chunk) {
    unsigned short (*S)[CPAD] = Sc[chunk & 1];

    // V frags for this chunk: issue early, consumed after the barrier
    short8 vf[4];
    #pragma unroll
    for (int ks = 0; ks < 4; ++ks) vf[ks] = ld8(vb0 + chunk * 128 + ks * 32 + kk);

    // ---- QK + exp: wave owns chunk-local cols [wave*32, wave*32+32) ----
    #pragma unroll
    for (int ct = 0; ct < 2; ++ct) {
      int s = chunk * 2 + ct;
      if (s < 7) {   // prefetch next step's K/pos frags
        int kcol = ((s + 1) >> 1) * 128 + wave * 32 + ((s + 1) & 1) * 16;
        const unsigned short* kb = kwb + kcol * DH_;
        const unsigned short* pb = posb + kcol * DH_;
        nb0 = ld8(kb + lc16 * DH_ + kk);
        nb1 = ld8(kb + lc16 * DH_ + 32 + kk);
        np0 = ld8(pb + lc16 * DH_ + kk);
        np1 = ld8(pb + lc16 * DH_ + 32 + kk);
      }
      int kcol = chunk * 128 + wave * 32 + ct * 16;
      floatx4 mk = *(const floatx4*)&mb2[kcol + quad * 4];
      floatx4 c[4];
      #pragma unroll
      for (int rt = 0; rt < 4; ++rt) {
        c[rt] = (floatx4){0.f, 0.f, 0.f, 0.f};
        c[rt] = MFMA16(cb0, aq[rt][0], c[rt]);   // A=K-tile, B=Q-rows
        c[rt] = MFMA16(cb1, aq[rt][1], c[rt]);
        c[rt] = MFMA16(cp0, ap[rt][0], c[rt]);
        c[rt] = MFMA16(cp1, ap[rt][1], c[rt]);
      }
      int lcol = wave * 32 + ct * 16 + quad * 4;   // chunk-local col base
      #pragma unroll
      for (int rt = 0; rt < 4; ++rt) {
        ushort4v pv;
        float sum = 0.f;
        #pragma unroll
        for (int r = 0; r < 4; ++r) {
          float e = __builtin_exp2f(c[rt][r] * SCALE2 + mk[r]);
          sum += e;
          pv[r] = f2b(e);
        }
        rs[rt] += sum;
        *(ushort4v*)&S[rt * 16 + lc16][lcol] = pv;
      }
      cb0 = nb0; cb1 = nb1; cp0 = np0; cp1 = np1;
    }
    __syncthreads();   // probs chunk ready (also: prior chunk fully consumed)

    // ---- PV over this chunk: wave owns d-slice [wave*16, +16) ----
    #pragma unroll
    for (int ks = 0; ks < 4; ++ks) {
      #pragma unroll
      for (int rt = 0; rt < 4; ++rt) {
        short8 pa = ld8(&S[rt * 16 + lc16][ks * 32 + kk]);
        o[rt] = MFMA16(pa, vf[ks], o[rt]);
      }
    }
    // no second barrier: next chunk writes the other Sc buffer
  }

  // ---- row-sum: reduce across quads, then across waves via LDS ----
  #pragma unroll
  for (int rt = 0; rt < 4; ++rt) {
    rs[rt] += __shfl_xor(rs[rt], 16, 64);
    rs[rt] += __shfl_xor(rs[rt], 32, 64);
  }
  if (quad == 0) {
    #pragma unroll
    for (int rt = 0; rt < 4; ++rt) red[rt * 16 + lc16][wave] = rs[rt];
  }
  __syncthreads();

  #pragma unroll
  for (int rt = 0; rt < 4; ++rt) {
    #pragma unroll
    for (int r = 0; r < 4; ++r) {
      int sl = rt * 16 + quad * 4 + r;
      float inv = 1.0f / (red[sl][0] + red[sl][1] + red[sl][2] + red[sl][3]);
      int s = qt * 64 + sl;
      out[((b << 9) + s) * H_ + h * DH_ + wave * 16 + lc16] = o[rt][r] * inv;
    }
  }
}

// ---------------------------------------------------------------------------
// host launcher
// ---------------------------------------------------------------------------
extern "C" void kernel_launch(void* const* d_in, const int* in_sizes, int n_in,
                              void* d_out, int out_size, void* d_ws, size_t ws_size,
                              hipStream_t stream) {
  (void)in_sizes; (void)n_in; (void)out_size; (void)ws_size;
  const float* hid  = (const float*)d_in[0];
  const float* ctx  = (const float*)d_in[1];
  const int*   mask = (const int*)d_in[2];
  const float* Wq   = (const float*)d_in[3];
  const float* bq   = (const float*)d_in[4];
  const float* Wk   = (const float*)d_in[5];
  const float* bk   = (const float*)d_in[6];
  const float* Wv   = (const float*)d_in[7];
  const float* bv   = (const float*)d_in[8];
  const float* pos  = (const float*)d_in[9];

  char* ws = (char*)d_ws;
  size_t off = 0;
  auto alloc = [&](size_t bytes) { char* p = ws + off; off = (off + bytes + 255) & ~(size_t)255; return p; };
  unsigned short* Xh = (unsigned short*)alloc((size_t)SEG_X * 2);
  unsigned short* Xc = (unsigned short*)alloc((size_t)SEG_X * 2);
  unsigned short* Wa = (unsigned short*)alloc((size_t)3 * SEG_W1 * 2);
  float*          Ba = (float*)alloc((size_t)NTOT * 4);
  unsigned short* qw = (unsigned short*)alloc((size_t)BH_ * SQ_ * DH_ * 2);
  unsigned short* kw = (unsigned short*)alloc((size_t)BH_ * SK_ * DH_ * 2);
  unsigned short* vt = (unsigned short*)alloc((size_t)BH_ * DH_ * SK_ * 2);
  unsigned short* Pb = (unsigned short*)alloc((size_t)SQ_ * DH_ * 2);

  int pack_blocks = (SEG_PE / 4 + 255) / 256;
  pack_kernel<<<pack_blocks, 256, 0, stream>>>(hid, ctx, Wq, Wk, Wv, bq, bk, bv, pos, Xh, Xc, Wa, Ba, Pb);
  qkv_gemm<<<32 * 18, 256, 0, stream>>>(Xh, Xc, Wa, Ba, Pb, qw, kw, vt);
  attn_kernel<<<BH_ * 8, 256, 0, stream>>>(qw, kw, vt, Pb, mask, (float*)d_out);
}